// Round 4
// baseline (198.038 us; speedup 1.0000x reference)
//
#include <hip/hip_runtime.h>
#include <math.h>

#define BB 32
#define NN 1024
#define DD 128

typedef __bf16 bf16;
typedef bf16 bf16x4 __attribute__((ext_vector_type(4)));
typedef bf16 bf16x8 __attribute__((ext_vector_type(8)));
typedef float f32x4 __attribute__((ext_vector_type(4)));
typedef float f32x16 __attribute__((ext_vector_type(16)));

#define MFMA16(a, b, c) __builtin_amdgcn_mfma_f32_16x16x32_bf16(a, b, c, 0, 0, 0)
#define MFMA32(a, b, c) __builtin_amdgcn_mfma_f32_32x32x16_bf16(a, b, c, 0, 0, 0)

__device__ inline bf16x4 swap32(bf16x4 v) {
    union { bf16x4 h; int i[2]; } u, r;
    u.h = v;
    r.i[0] = __shfl_xor(u.i[0], 32, 64);
    r.i[1] = __shfl_xor(u.i[1], 32, 64);
    return r.h;
}

// ---------------- K0: prep (all global accesses coalesced via LDS tile) ----------
// Xbf[b*N+n][0:128]=bf16(P); Pq=bf16(P*wc); Ptp[b][d][n]=bf16(P[b][n][d]);
// t[b][n]=P_n.wa  (wb is dead: constant over softmax axis)
#define LTS 133
__global__ __launch_bounds__(256) void k_prep(const float* __restrict__ P,
                                              const float* __restrict__ w_itr,
                                              bf16* __restrict__ Xbf,
                                              bf16* __restrict__ Pq,
                                              bf16* __restrict__ Ptp,
                                              float* __restrict__ t) {
    __shared__ float Lt[64 * LTS];
    int tid = threadIdx.x;
    int b = blockIdx.x >> 4, g = blockIdx.x & 15;
    int n0 = g * 64;
    long base = ((long)b * NN + n0) * DD;
#pragma unroll
    for (int i = 0; i < 8; ++i) {
        int idx = tid + i * 256;           // 0..2047 f4-chunks
        int row = idx >> 5, c4 = idx & 31;
        *(float4*)&Lt[row * LTS + c4 * 4] = *(const float4*)&P[base + row * 128 + c4 * 4];
    }
    __syncthreads();
    {   // t = P . wa, k interleaved to avoid bank conflicts
        int row = tid >> 2, q = tid & 3;
        float s = 0.f;
#pragma unroll
        for (int kk = 0; kk < 32; ++kk) {
            int k = 4 * kk + q;
            s += Lt[row * LTS + k] * w_itr[k];
        }
        s += __shfl_xor(s, 1);
        s += __shfl_xor(s, 2);
        if (q == 0) t[(long)b * NN + n0 + row] = s;
    }
    const float* wc = w_itr + 2 * DD;
#pragma unroll
    for (int i = 0; i < 4; ++i) {
        int idx = tid + i * 256;           // 0..1023 8-elem chunks
        int row = idx >> 4, seg = idx & 15;
        float4 va = *(const float4*)&Lt[row * LTS + seg * 8];
        float4 vb = *(const float4*)&Lt[row * LTS + seg * 8 + 4];
        float4 wa4 = *(const float4*)&wc[seg * 8];
        float4 wb4 = *(const float4*)&wc[seg * 8 + 4];
        float fv[8] = {va.x, va.y, va.z, va.w, vb.x, vb.y, vb.z, vb.w};
        float wv[8] = {wa4.x, wa4.y, wa4.z, wa4.w, wb4.x, wb4.y, wb4.z, wb4.w};
        bf16x8 xv, qv;
#pragma unroll
        for (int e = 0; e < 8; ++e) {
            xv[e] = (bf16)fv[e];
            qv[e] = (bf16)(fv[e] * wv[e]);
        }
        long rowg = (long)b * NN + n0 + row;
        *(bf16x8*)&Xbf[rowg * 128 + seg * 8] = xv;
        *(bf16x8*)&Pq[rowg * 128 + seg * 8] = qv;
    }
#pragma unroll
    for (int i = 0; i < 4; ++i) {
        int idx = tid + i * 256;           // d-major chunks
        int d = idx >> 3, c = idx & 7;
        bf16x8 v;
#pragma unroll
        for (int e = 0; e < 8; ++e) v[e] = (bf16)Lt[(c * 8 + e) * LTS + d];
        *(bf16x8*)&Ptp[((long)b * DD + d) * NN + n0 + c * 8] = v;
    }
}

// ---------------- K0b: weight transpose (LDS-tiled) ----------------
// WtG[mat*128 + col][k] = bf16(w_mat[k][col])
__global__ __launch_bounds__(256) void k_prepw(const float* __restrict__ w1,
                                               const float* __restrict__ w2,
                                               const float* __restrict__ w3,
                                               bf16* __restrict__ WtG) {
    __shared__ float Lw[32][33];
    int bi = blockIdx.x;                 // 96 = 3 mats * 8 kt * 4 ct
    int mat = bi >> 5, rem = bi & 31;
    int kt = rem >> 2, ct = rem & 3;
    const float* wsrc = (mat == 0) ? w1 : ((mat == 1) ? w2 : w3);
    int tid = threadIdx.x;
#pragma unroll
    for (int p = 0; p < 4; ++p) {
        int idx = tid + p * 256;
        int kr = idx >> 5, c = idx & 31;
        Lw[kr][c] = wsrc[(kt * 32 + kr) * DD + ct * 32 + c];
    }
    __syncthreads();
    int colg = tid >> 3, kq = tid & 7;
    bf16x4 v;
#pragma unroll
    for (int e = 0; e < 4; ++e) v[e] = (bf16)Lw[kq * 4 + e][colg];
    *(bf16x4*)&WtG[(mat * 128 + ct * 32 + colg) * 256 + kt * 32 + kq * 4] = v;
}

// ---------------- K1: fused attention + gated MLP ----------------
// 4 waves = 2 row-groups (rg: 32 q-rows) x 2 key-halves (kh: 512 keys).
// S^T = K*Q^T; P=exp(S+t); O^T = V^T*P (no-max streaming softmax, logits tiny).
// Tail: X=[P|attn] assembled in LDS (bf16), 3 fused GEMMs vs WtG, out written.
__global__ __launch_bounds__(256, 2) void k_attn(const bf16* __restrict__ Xbf,
                                                 const bf16* __restrict__ Pq,
                                                 const bf16* __restrict__ Ptp,
                                                 const float* __restrict__ t,
                                                 const bf16* __restrict__ WtG,
                                                 const float* __restrict__ P,
                                                 const float* __restrict__ b1,
                                                 const float* __restrict__ b2,
                                                 const float* __restrict__ b3,
                                                 float* __restrict__ out) {
    __shared__ __align__(16) char smem[72704];
    bf16* Kt = (bf16*)smem;                  // [2][64][136]  (34816 B)
    bf16* Vt = (bf16*)(smem + 34816);        // [2][128][72]  (36864 B, end 71680)
    float* tsh = (float*)(smem + 71680);     // [2][64]
    float* lbuf = (float*)(smem + 72192);    // [4][32]
    float* Obuf = (float*)smem;              // alias: [2][128][33] f32 (33792 B)
    bf16* Xsh = (bf16*)(smem + 34816);       // alias: [64][264] bf16 (33792 B)

    const int tid = threadIdx.x;
    const int w = tid >> 6, lane = tid & 63;
    const int col = lane & 31, q = lane >> 5;
    const int kh = w >> 1, rg = w & 1;
    const int b = blockIdx.x & 31, qt = blockIdx.x >> 5;
    const long qrow0 = (long)b * NN + qt * 64;
    const long qbase = qrow0 + rg * 32;

    bf16x8 Qb[8];
#pragma unroll
    for (int c = 0; c < 8; ++c)
        Qb[c] = *(const bf16x8*)&Pq[(qbase + col) * 128 + c * 16 + q * 8];

    f32x16 O[4];
#pragma unroll
    for (int mt = 0; mt < 4; ++mt)
#pragma unroll
        for (int r = 0; r < 16; ++r) O[mt][r] = 0.f;
    float lsum = 0.f;

    float4 kr[8], vr[8];
    float tr = 0.f;
    auto loadKV = [&](int jt) {
#pragma unroll
        for (int i = 0; i < 8; ++i) {
            int idx = tid + i * 256;
            int h = idx >> 10, rem = idx & 1023;
            kr[i] = *(const float4*)&Xbf[((long)b * NN + h * 512 + jt * 64 + (rem >> 4)) * 128 +
                                         (rem & 15) * 8];
            vr[i] = *(const float4*)&Ptp[((long)b * DD + (rem >> 3)) * NN + h * 512 + jt * 64 +
                                         (rem & 7) * 8];
        }
        tr = (tid < 128) ? t[(long)b * NN + (tid >> 6) * 512 + jt * 64 + (tid & 63)] : 0.f;
    };

    loadKV(0);
    for (int jt = 0; jt < 8; ++jt) {
        __syncthreads();
#pragma unroll
        for (int i = 0; i < 8; ++i) {
            int idx = tid + i * 256;
            int h = idx >> 10, rem = idx & 1023;
            *(float4*)&Kt[h * (64 * 136) + (rem >> 4) * 136 + (rem & 15) * 8] = kr[i];
            *(float4*)&Vt[h * (128 * 72) + (rem >> 3) * 72 + (rem & 7) * 8] = vr[i];
        }
        if (tid < 128) tsh[tid] = tr;
        __syncthreads();
        if (jt < 7) loadKV(jt + 1);

        const bf16* KtH = Kt + kh * (64 * 136);
        const bf16* VtH = Vt + kh * (128 * 72);
        const float* tH = tsh + kh * 64;
#pragma unroll
        for (int kt = 0; kt < 2; ++kt) {
            f32x16 S;
#pragma unroll
            for (int r = 0; r < 16; ++r) S[r] = 0.f;
#pragma unroll
            for (int c = 0; c < 8; ++c)
                S = MFMA32(*(const bf16x8*)&KtH[(kt * 32 + col) * 136 + c * 16 + q * 8],
                           Qb[c], S);
            float tqs[16];
#pragma unroll
            for (int i = 0; i < 4; ++i) {
                float4 tv = *(const float4*)&tH[kt * 32 + 8 * i + 4 * q];
                tqs[4 * i + 0] = tv.x; tqs[4 * i + 1] = tv.y;
                tqs[4 * i + 2] = tv.z; tqs[4 * i + 3] = tv.w;
            }
            float pv[16];
#pragma unroll
            for (int r = 0; r < 16; ++r) {
                float e = __expf(fminf(S[r] + tqs[r], 80.f));
                pv[r] = e;
                lsum += e;
            }
            bf16x4 Qd[4];
#pragma unroll
            for (int i = 0; i < 4; ++i)
#pragma unroll
                for (int e = 0; e < 4; ++e) Qd[i][e] = (bf16)pv[4 * i + e];
            bf16x4 sA = q ? Qd[0] : Qd[1];
            bf16x4 rA = swap32(sA);
            bf16x4 sB = q ? Qd[2] : Qd[3];
            bf16x4 rB = swap32(sB);
            bf16x4 lo0 = q ? rA : Qd[0], hi0 = q ? Qd[1] : rA;
            bf16x4 lo1 = q ? rB : Qd[2], hi1 = q ? Qd[3] : rB;
            bf16x8 f0, f1;
#pragma unroll
            for (int e = 0; e < 4; ++e) {
                f0[e] = lo0[e]; f0[4 + e] = hi0[e];
                f1[e] = lo1[e]; f1[4 + e] = hi1[e];
            }
#pragma unroll
            for (int mt = 0; mt < 4; ++mt) {
                O[mt] = MFMA32(*(const bf16x8*)&VtH[(mt * 32 + col) * 72 + kt * 32 + q * 8],
                               f0, O[mt]);
                O[mt] = MFMA32(*(const bf16x8*)&VtH[(mt * 32 + col) * 72 + kt * 32 + 16 + q * 8],
                               f1, O[mt]);
            }
        }
    }

    // ---- merge key-halves into Xsh = [P | attn] (bf16) ----
    float l2 = lsum + __shfl_xor(lsum, 32, 64);
    if (q == 0) lbuf[(kh * 2 + rg) * 32 + col] = l2;
    __syncthreads();                    // Kt/Vt dead; lbuf visible
    if (kh == 1) {
#pragma unroll
        for (int mt = 0; mt < 4; ++mt)
#pragma unroll
            for (int r = 0; r < 16; ++r) {
                int d = mt * 32 + (r & 3) + 8 * (r >> 2) + 4 * q;
                Obuf[(rg * 128 + d) * 33 + col] = O[mt][r];
            }
    } else {
        // kh0 (tids 0..127): stage P-half of X coalesced from global
        int tl = tid;
#pragma unroll
        for (int i = 0; i < 8; ++i) {
            int idx = tl + i * 128;     // 0..1023
            int row = idx >> 4, seg = idx & 15;
            *(bf16x8*)&Xsh[row * 264 + seg * 8] =
                *(const bf16x8*)&Xbf[(qrow0 + row) * 128 + seg * 8];
        }
    }
    __syncthreads();
    if (kh == 0) {
        float linv = 1.f / (lbuf[(0 * 2 + rg) * 32 + col] + lbuf[(1 * 2 + rg) * 32 + col]);
#pragma unroll
        for (int mt = 0; mt < 4; ++mt)
#pragma unroll
            for (int r = 0; r < 16; ++r) {
                int d = mt * 32 + (r & 3) + 8 * (r >> 2) + 4 * q;
                float v = (O[mt][r] + Obuf[(rg * 128 + d) * 33 + col]) * linv;
                Xsh[(rg * 32 + col) * 264 + 128 + d] = (bf16)v;
            }
    }
    __syncthreads();

    // ---- fused gated MLP: Y_m = X @ W_m ----
    const int ln = lane & 15, q3 = lane >> 4;
    const int ch = w >> 1, rg2 = w & 1;  // rows rg2*32.., cols ch*64..
    f32x4 stz[2][4], str[2][4];
#pragma unroll
    for (int mat = 0; mat < 3; ++mat) {
        f32x4 acc[2][4];
#pragma unroll
        for (int mt = 0; mt < 2; ++mt)
#pragma unroll
            for (int nt = 0; nt < 4; ++nt) acc[mt][nt] = (f32x4){0.f, 0.f, 0.f, 0.f};
#pragma unroll
        for (int kc = 0; kc < 8; ++kc) {
            bf16x8 Af0 = *(const bf16x8*)&Xsh[(rg2 * 32 + ln) * 264 + kc * 32 + q3 * 8];
            bf16x8 Af1 = *(const bf16x8*)&Xsh[(rg2 * 32 + 16 + ln) * 264 + kc * 32 + q3 * 8];
#pragma unroll
            for (int nt = 0; nt < 4; ++nt) {
                bf16x8 Bf = *(const bf16x8*)&WtG[(mat * 128 + ch * 64 + nt * 16 + ln) * 256 +
                                                 kc * 32 + q3 * 8];
                acc[0][nt] = MFMA16(Af0, Bf, acc[0][nt]);
                acc[1][nt] = MFMA16(Af1, Bf, acc[1][nt]);
            }
        }
        const float* bp = (mat == 0) ? b1 : ((mat == 1) ? b2 : b3);
#pragma unroll
        for (int mt = 0; mt < 2; ++mt)
#pragma unroll
            for (int nt = 0; nt < 4; ++nt) {
                int colc = ch * 64 + nt * 16 + ln;
                float bb = bp[colc];
#pragma unroll
                for (int r = 0; r < 4; ++r) {
                    float y = acc[mt][nt][r] + bb;
                    if (mat == 0) stz[mt][nt][r] = tanhf(y);
                    else if (mat == 1) str[mt][nt][r] = 1.f / (1.f + __expf(-y));
                    else {
                        float fg = 1.f / (1.f + __expf(-y));
                        long row = qrow0 + rg2 * 32 + mt * 16 + q3 * 4 + r;
                        float p = P[row * DD + colc];
                        out[row * DD + colc] = str[mt][nt][r] * p + fg * stz[mt][nt][r];
                    }
                }
            }
    }
}

extern "C" void kernel_launch(void* const* d_in, const int* in_sizes, int n_in,
                              void* d_out, int out_size, void* d_ws, size_t ws_size,
                              hipStream_t stream) {
    const float* P     = (const float*)d_in[0];
    const float* w_itr = (const float*)d_in[1];
    const float* w1    = (const float*)d_in[2];
    const float* w2    = (const float*)d_in[3];
    const float* w3    = (const float*)d_in[4];
    const float* b1    = (const float*)d_in[5];
    const float* b2    = (const float*)d_in[6];
    const float* b3    = (const float*)d_in[7];
    float* out = (float*)d_out;

    char* wsb = (char*)d_ws;
    bf16* Xbf  = (bf16*)(wsb);                    //  8,388,608 B
    bf16* Pq   = (bf16*)(wsb + 8388608);          //  8,388,608 B
    bf16* Ptp  = (bf16*)(wsb + 16777216);         //  8,388,608 B
    float* tws = (float*)(wsb + 25165824);        //    131,072 B
    bf16* WtG  = (bf16*)(wsb + 25296896);         //    196,608 B  (total ~25.5 MB)

    k_prep<<<dim3(BB * 16), dim3(256), 0, stream>>>(P, w_itr, Xbf, Pq, Ptp, tws);
    k_prepw<<<dim3(96), dim3(256), 0, stream>>>(w1, w2, w3, WtG);
    k_attn<<<dim3(512), dim3(256), 0, stream>>>(Xbf, Pq, Ptp, tws, WtG, P, b1, b2, b3, out);
}